// Round 7
// baseline (233.310 us; speedup 1.0000x reference)
//
#include <hip/hip_runtime.h>

// FinDiffNonUniform: out[n,b] = sum_{s<7} coef[n,s] * y[n + off[n,s], b]
// N=8192, B=4096, S=7, fp32.
//
// Round-8: barrier-free per-wave streaming pipeline, RACE-FIXED.
// Round-7's tripwire failure was a real race: edge block bn==0 skipped 3
// stores at iter 0, so its VMEM queue held 3 fewer ops than the vmcnt
// accounting assumed -> vmcnt(8) left current-window rows in flight ->
// ds_read of un-landed LDS. (Confirmed: the compiler inserts NO wait on the
// gll->ds_read dep; explicit vmcnt is the only protection.)
// Fixes: (1) block-uniform VMEM schedule -- ALL blocks issue all 4 stores
// every iter (edge rows store garbage, fixed up after an explicit vmcnt(0)
// drain); (2) iteration order [wait -> ds_read -> STAGE -> compute -> store]:
// with the wait FIRST, any unexpected extra VMEM op is younger than the rows
// the wait covers => wait becomes MORE conservative, never less. Counts:
// iter0 vmcnt(2) (12 prologue loads, need rows 0..9); steady vmcnt(6)
// (2 newest loads + 4 prev-iter stores younger than newest needed row).
// Each wave owns a 16-slot x 1KB LDS ring (64KB/block, 2 blocks/CU); 512
// blocks fully co-resident; steady in-flight = 6KB/wave x 8 waves = 48KB/CU.

#define FD_N   8192
#define FD_B   4096
#define FD_S   7
#define HALO   3
#define STEP   4
#define NITER  16
#define SPAN   (STEP * NITER)        // 64 rows per block
#define NBN    (FD_N / SPAN)         // 128 n-blocks
#define NWG    (NBN * 4)             // 512 blocks = 2/CU exactly
#define RING   16                    // slots per wave ring
#define SLOTF  256                   // floats per slot (1 KB wave slice)
#define WIN    (STEP + 2 * HALO)     // 10 rows read per iter

typedef float v4f __attribute__((ext_vector_type(4)));
typedef unsigned int u32;
typedef const __attribute__((address_space(1))) u32* gptr_t;
typedef __attribute__((address_space(3))) u32* lptr_t;

__global__ __launch_bounds__(256, 2) void
_FinDiffNonUniform_51608327029442_kernel(const float* __restrict__ y,
                                         const float* __restrict__ coef,
                                         const int*   __restrict__ offs,
                                         float*       __restrict__ out) {
    const int bn    = blockIdx.x >> 2;
    const int chunk = blockIdx.x & 3;
    const int n0    = bn * SPAN;
    const int tid   = threadIdx.x;
    const int wave  = tid >> 6;
    const int lane  = tid & 63;
    const int col   = (chunk << 10) + (wave << 8) + (lane << 2);

    __shared__ float lds[4 * RING * SLOTF];              // 64 KB
    float* const wbase = lds + wave * (RING * SLOTF);    // per-wave ring

    const bool lo = (bn == 0);
    const bool hi = (bn == NBN - 1);

    // Stage relative row r into ring slot r&15. Clamped rows only feed
    // outputs that are overwritten by the fixup below.
    auto STAGE = [&](int r) {
        int g = n0 - HALO + r;
        g = g < 0 ? 0 : g;
        g = g > FD_N - 1 ? FD_N - 1 : g;
        const float* src = y + (size_t)g * FD_B + col;           // per-lane
        __builtin_amdgcn_global_load_lds(
            (gptr_t)src,
            (lptr_t)((u32*)wbase + (r & (RING - 1)) * SLOTF),    // wave-uniform
            16, 0, 0);
    };

    // Prologue: rows 0..11 in flight (12 loads, uniform across all blocks).
#pragma unroll
    for (int r = 0; r < 12; ++r) STAGE(r);

#pragma unroll
    for (int k = 0; k < NITER; ++k) {
        // Counted wait FIRST: guarantees rows <= 4k+9 have landed. Any VMEM
        // op issued since those rows only makes this wait stricter (safe).
        if (k == 0) asm volatile("s_waitcnt vmcnt(2)" ::: "memory");
        else        asm volatile("s_waitcnt vmcnt(6)" ::: "memory");

        // Read the 10-row window once from the ring.
        v4f w[WIN];
#pragma unroll
        for (int m = 0; m < WIN; ++m)
            w[m] = *reinterpret_cast<const v4f*>(
                wbase + ((4 * k + m) & (RING - 1)) * SLOTF + (lane << 2));

        // Keep the prefetch AFTER the reads (widens slot-reuse gap).
        asm volatile("" ::: "memory");

        // Prefetch rows 4k+12..15 into slots (4k-4..4k-1)&15 -- disjoint
        // from the read window (4k..4k+9)&15. Dead at the last iter (no
        // later wait depends on its count).
        if (k < NITER - 1) {
            STAGE(4 * k + 12);
            STAGE(4 * k + 13);
            STAGE(4 * k + 14);
            STAGE(4 * k + 15);
        }

        // Block-uniform coefficients (SMEM; harmless if VMEM, see above).
        float c[STEP][FD_S];
#pragma unroll
        for (int j = 0; j < STEP; ++j)
#pragma unroll
            for (int s = 0; s < FD_S; ++s)
                c[j][s] = coef[(size_t)(n0 + 4 * k + j) * FD_S + s];

        v4f acc[STEP];
#pragma unroll
        for (int j = 0; j < STEP; ++j) acc[j] = (v4f){0.f, 0.f, 0.f, 0.f};

        // Row m feeds acc[j] with stencil index s = m - j in [0,7).
#pragma unroll
        for (int m = 0; m < WIN; ++m)
#pragma unroll
            for (int j = 0; j < STEP; ++j) {
                const int s = m - j;
                if (s >= 0 && s < FD_S)
                    acc[j] += c[j][s] * w[m];
            }

        // ALWAYS all 4 stores (uniform vmcnt accounting for every block);
        // edge rows store garbage and are overwritten by the fixup.
#pragma unroll
        for (int j = 0; j < STEP; ++j)
            __builtin_nontemporal_store(
                acc[j],
                reinterpret_cast<v4f*>(out + (size_t)(n0 + 4 * k + j) * FD_B + col));
    }

    // Fixup: the 3 one-sided rows at each end, via real offsets. Drain all
    // VMEM first so the garbage stores cannot land after these stores.
    if (lo || hi) {
        asm volatile("s_waitcnt vmcnt(0)" ::: "memory");
        const int nbeg = lo ? 0 : FD_N - HALO;
#pragma unroll
        for (int t = 0; t < HALO; ++t) {
            const int n = nbeg + t;
            const float* __restrict__ cc = coef + (size_t)n * FD_S;
            const int*   __restrict__ oo = offs + (size_t)n * FD_S;
            v4f acc = (v4f){0.f, 0.f, 0.f, 0.f};
#pragma unroll
            for (int s = 0; s < FD_S; ++s) {
                const v4f v = *reinterpret_cast<const v4f*>(
                    y + (size_t)(n + oo[s]) * FD_B + col);
                acc += cc[s] * v;
            }
            *reinterpret_cast<v4f*>(out + (size_t)n * FD_B + col) = acc;
        }
    }
}

extern "C" void kernel_launch(void* const* d_in, const int* in_sizes, int n_in,
                              void* d_out, int out_size, void* d_ws, size_t ws_size,
                              hipStream_t stream) {
    const float* y    = (const float*)d_in[0];
    const float* coef = (const float*)d_in[1];
    const int*   offs = (const int*)d_in[2];
    float*       out  = (float*)d_out;

    _FinDiffNonUniform_51608327029442_kernel<<<NWG, 256, 0, stream>>>(y, coef, offs, out);
}